// Round 13
// baseline (184.642 us; speedup 1.0000x reference)
//
#include <hip/hip_runtime.h>
#include <cstdint>
#include <cmath>

// ---------------- problem constants ----------------
#define BS    2
#define CC    64
#define FLAT  16384
#define NN    2048
#define KK    256
#define EPSBN 1e-5f
#define TINYF 1.17549435e-38f
#define PE_SCALE -0.14391156831212787f
#define JAX_PARTITIONABLE 1

// ---------------- workspace layout (float offsets) ----------------
#define OFF_XI    0                          // [BS][NN][CC]
#define OFF_XI1   (OFF_XI   + BS*NN*CC)      // [BS][NN][32]
#define OFF_PROB  (OFF_XI1  + BS*NN*32)      // [BS][NN]
#define OFF_LOGP  (OFF_PROB + BS*NN)         // [BS][NN]
#define OFF_NEK   (OFF_LOGP + BS*NN)         // [BS][KK]
#define OFF_TF    (OFF_NEK  + BS*KK)         // [BS][KK][CC]
#define OFF_M1    (OFF_TF   + BS*KK*CC)      // [BS][KK][32]
#define OFF_DELTA (OFF_M1   + BS*KK*32)      // [BS][NN][CC]
#define OFF_WF    (OFF_DELTA+ BS*NN*CC)      // [256][64]
#define OFF_BF    (OFF_WF   + 256*CC)        // [64]
#define OFF_INV   (OFF_BF   + CC)            // [BS][FLAT] ints

// ---------------- threefry2x32 ----------------
__device__ __forceinline__ uint32_t rotl32(uint32_t x, int r) {
  return (x << r) | (x >> (32 - r));
}
__device__ __forceinline__ void tf2x32(uint32_t k0, uint32_t k1,
                                       uint32_t& x0, uint32_t& x1) {
  uint32_t k2 = k0 ^ k1 ^ 0x1BD11BDAu;
  x0 += k0; x1 += k1;
#define TFR(r) { x0 += x1; x1 = rotl32(x1, r); x1 ^= x0; }
  TFR(13) TFR(15) TFR(26) TFR(6)  x0 += k1; x1 += k2 + 1u;
  TFR(17) TFR(29) TFR(16) TFR(24) x0 += k2; x1 += k0 + 2u;
  TFR(13) TFR(15) TFR(26) TFR(6)  x0 += k0; x1 += k1 + 3u;
  TFR(17) TFR(29) TFR(16) TFR(24) x0 += k1; x1 += k2 + 4u;
  TFR(13) TFR(15) TFR(26) TFR(6)  x0 += k2; x1 += k0 + 5u;
#undef TFR
}
__device__ __forceinline__ void jax_key(int b, uint32_t& k0, uint32_t& k1) {
#if JAX_PARTITIONABLE
  uint32_t x0 = 0u, x1 = (uint32_t)b;
  tf2x32(0u, 42u, x0, x1);
  k0 = x0; k1 = x1;
#else
  uint32_t a0 = 0u, a1 = 2u, c0 = 1u, c1 = 3u;
  tf2x32(0u, 42u, a0, a1);
  tf2x32(0u, 42u, c0, c1);
  if (b == 0) { k0 = a0; k1 = c0; } else { k0 = a1; k1 = c1; }
#endif
}
__device__ __forceinline__ uint32_t jax_bits(uint32_t k0, uint32_t k1, uint32_t i) {
#if JAX_PARTITIONABLE
  uint32_t x0 = 0u, x1 = i;
  tf2x32(k0, k1, x0, x1);
  return x0 ^ x1;
#else
  const uint32_t half = (uint32_t)(KK * NN) / 2u;
  uint32_t x0, x1;
  if (i < half) { x0 = i; x1 = i + half; tf2x32(k0, k1, x0, x1); return x0; }
  else          { x0 = i - half; x1 = i; tf2x32(k0, k1, x0, x1); return x1; }
#endif
}

// ---------------- K0: fold resize weights + init inverse mask map
__global__ void k0_fold(const float* __restrict__ w_r1, const float* __restrict__ b_r1,
                        const float* __restrict__ w_r2, const float* __restrict__ b_r2,
                        float* __restrict__ ws) {
  int c = blockIdx.x;      // 0..255
  int co = threadIdx.x;    // 0..63
  float acc = 0.f;
  for (int f = 0; f < 128; ++f)
    acc += w_r1[c * 128 + f] * w_r2[f * 64 + co];
  ws[OFF_WF + c * 64 + co] = acc;
  if (blockIdx.x == 0) {
    float bb = b_r2[co];
    for (int f = 0; f < 128; ++f) bb += b_r1[f] * w_r2[f * 64 + co];
    ws[OFF_BF + co] = bb;
  }
  int* inv = (int*)(ws + OFF_INV);
  int t = blockIdx.x * 64 + threadIdx.x;       // 0..16383
  inv[t] = -1;
  inv[t + BS * FLAT / 2] = -1;
}

// ---------------- K1: 32 threads per n: xi, prob/logp, xi1, inv map
__global__ __launch_bounds__(256) void k1_xi(
    const float* __restrict__ input, const int* __restrict__ midx,
    const float* __restrict__ w_ne1, const float* __restrict__ b_ne1,
    const float* __restrict__ g_ne,  const float* __restrict__ be_ne,
    const float* __restrict__ w_ne2, const float* __restrict__ b_ne2,
    const float* __restrict__ w_p1,  const float* __restrict__ g_p1,
    float* __restrict__ ws) {
  int tid = threadIdx.x;
  int j = tid & 31, nl = tid >> 5;             // 8 n per block
  int bn = blockIdx.x * 8 + nl;                // grid = BS*NN/8 = 512
  int b = bn >> 11, n = bn & (NN - 1);
  int pos = midx[b * NN + n];
  __shared__ float xis[8][66];
  float d = expf((float)(2 * j) * PE_SCALE);
  float ang = (float)pos * d;
  float xs = sinf(ang) + input[((size_t)(b * CC + 2 * j)) * FLAT + pos];
  float xc = cosf(ang) + input[((size_t)(b * CC + 2 * j + 1)) * FLAT + pos];
  xis[nl][2 * j] = xs; xis[nl][2 * j + 1] = xc;
  float2 v2; v2.x = xs; v2.y = xc;
  ((float2*)(ws + OFF_XI + (size_t)(b * NN + n) * CC))[j] = v2;
  __syncthreads();
  float zne = b_ne1[j];
  float z1 = 0.f;
#pragma unroll
  for (int c2 = 0; c2 < CC; ++c2) {
    float xv = xis[nl][c2];
    zne += xv * w_ne1[c2 * 32 + j];
    z1  += xv * w_p1[c2 * 32 + j];
  }
  float ane = g_ne[j] / sqrtf(1.f + EPSBN);
  float h = fmaxf(0.f, zne * ane + be_ne[j]);
  float pp = h * w_ne2[j];
  for (int off = 16; off > 0; off >>= 1) pp += __shfl_down(pp, off, 32);
  if (j == 0) {
    float prob = 1.f / (1.f + expf(-(pp + b_ne2[0])));
    ws[OFF_PROB + b * NN + n] = prob;
    ws[OFF_LOGP + b * NN + n] = logf(prob);
    ((int*)(ws + OFF_INV))[b * FLAT + pos] = n;
  }
  float a1 = g_p1[j] / sqrtf(1.f + EPSBN);
  ws[OFF_XI1 + (size_t)(b * NN + n) * 32 + j] = z1 * a1;
}

// ---------------- K2: categorical draw k for sample b; emit tf, ne_k, m1
__global__ __launch_bounds__(256) void k2_sample(
    const int* __restrict__ midx,
    const float* __restrict__ w_p1, const float* __restrict__ b_p1,
    const float* __restrict__ g_p1, const float* __restrict__ be_p1,
    float* __restrict__ ws) {
  int b = blockIdx.x >> 8, k = blockIdx.x & 255;
  int tid = threadIdx.x;
  uint32_t kb0, kb1;
  jax_key(b, kb0, kb1);
  const float* logp = ws + OFF_LOGP + b * NN;
  const float NEGINF = -__builtin_inff();
  float bv = NEGINF; int bn = NN;
#pragma unroll 1
  for (int r = 0; r < 8; ++r) {
    int n = r * 256 + tid;
    uint32_t bits = jax_bits(kb0, kb1, (uint32_t)(k * NN + n));
    float f = __uint_as_float(0x3f800000u | (bits >> 9)) - 1.0f;
    float u = fmaxf(TINYF, f + TINYF);
    float gmb = -logf(-logf(u));
    float v = logp[n] + gmb;
    if (v > bv || (v == bv && n < bn)) { bv = v; bn = n; }
  }
  __shared__ float sv[256];
  __shared__ int   sn[256];
  __shared__ float mpe[CC];
  sv[tid] = bv; sn[tid] = bn;
  __syncthreads();
  for (int s = 128; s > 0; s >>= 1) {
    if (tid < s) {
      float v2 = sv[tid + s]; int n2 = sn[tid + s];
      if (v2 > sv[tid] || (v2 == sv[tid] && n2 < sn[tid])) { sv[tid] = v2; sn[tid] = n2; }
    }
    __syncthreads();
  }
  int best = sn[0];
  if (tid == 0)
    ws[OFF_NEK + b * KK + k] = ws[OFF_PROB + b * NN + best];
  if (tid < CC) {
    int c = tid;
    ws[OFF_TF + (size_t)(b * KK + k) * CC + c] =
        ws[OFF_XI + (size_t)(b * NN + best) * CC + c];
    int pos = midx[b * NN + best];
    int jj = c >> 1;
    float ang = (float)pos * expf((float)(2 * jj) * PE_SCALE);
    mpe[c] = (c & 1) ? cosf(ang) : sinf(ang);
  }
  __syncthreads();
  if (tid < 32) {
    int jj = tid;
    float acc = b_p1[jj];
#pragma unroll
    for (int c = 0; c < CC; ++c) acc += mpe[c] * w_p1[c * 32 + jj];
    float a = g_p1[jj] / sqrtf(1.f + EPSBN);
    ws[OFF_M1 + (size_t)(b * KK + k) * 32 + jj] = acc * a + be_p1[jj];
  }
}

// ---------------- K3 fused v2: conflict-free geometry restored
// Per wave: kg spans 8 (2-way LDS read = free, m136), qg spans 8 (w2 reads
// 128B span = free), z[8][4], 4 k-passes, h on-the-fly. m1t half [32][128],
// no pad (conflicts are intra-row; writes lane-consecutive). LDS ~28 KB.
// r12's 16-kgl mapping caused 852K bank conflicts — reverted.
__global__ __launch_bounds__(256) void k3_fused(
    const float* __restrict__ w_p2, const float* __restrict__ b_p2,
    const float* __restrict__ g_p2, const float* __restrict__ be_p2,
    const float* __restrict__ w_p3, const float* __restrict__ b_p3,
    float* __restrict__ ws) {
  __shared__ __align__(16) float m1t[32 * 128];   // 16 KB, m1^T k-half [j][kl]
  __shared__ __align__(16) float w2s[1024];       // 4 KB
  __shared__ __align__(16) float Pis[4][256];     // 4 KB
  __shared__ __align__(16) float nekl[256];       // 1 KB
  __shared__ __align__(16) float xi1s[4][32];
  __shared__ __align__(16) float c2f[32];
  __shared__ __align__(16) float w3l[32];
  __shared__ __align__(16) float xIl[4 * 68], xEl[4 * 68];
  __shared__ float sI[4], sE[4];
  int tid = threadIdx.x;
  int b = blockIdx.x >> 9;                        // grid = BS*NN/4 = 1024
  int n0 = (blockIdx.x & 511) * 4;
  int nn = tid >> 6;                              // wave-uniform
  int kg = (tid >> 3) & 7;                        // 8 values per wave
  int qg = tid & 7;                               // 8 values per wave
  int q0 = qg * 4;
  // --- prologue ---
  for (int e = tid; e < 1024; e += 256) {
    int q = e & 31;
    w2s[e] = w_p2[e] * (g_p2[q] / sqrtf(1.f + EPSBN));
  }
  if (tid < 32) {
    c2f[tid] = b_p2[tid] * (g_p2[tid] / sqrtf(1.f + EPSBN)) + be_p2[tid];
    w3l[tid] = w_p3[tid];
  }
  if (tid < 128) {
    int n4 = tid >> 5, jx = tid & 31;
    xi1s[n4][jx] = ws[OFF_XI1 + (size_t)(b * NN + n0 + n4) * 32 + jx];
  }
  nekl[tid] = ws[OFF_NEK + b * KK + tid];
  float b3 = b_p3[0];
  __syncthreads();
  const float4* w2s4 = (const float4*)w2s;
  const float4 cv  = *(const float4*)&c2f[q0];
  const float4 w3v = *(const float4*)&w3l[q0];
#pragma unroll 1
  for (int kh = 0; kh < 2; ++kh) {
    // stage m1^T half: thread -> (kl = tid&127, jh = tid>>7); lane-consecutive
    // LDS writes (2-way, free); strided-64B global reads (L2-absorbed)
    {
      int kl = tid & 127, jh = tid >> 7;
      const float4* src = (const float4*)(ws + OFF_M1 +
                           (size_t)(b * KK + kh * 128 + kl) * 32 + jh * 16);
#pragma unroll
      for (int u = 0; u < 4; ++u) {
        float4 v = src[u];
        m1t[(jh * 16 + u * 4 + 0) * 128 + kl] = v.x;
        m1t[(jh * 16 + u * 4 + 1) * 128 + kl] = v.y;
        m1t[(jh * 16 + u * 4 + 2) * 128 + kl] = v.z;
        m1t[(jh * 16 + u * 4 + 3) * 128 + kl] = v.w;
      }
    }
    __syncthreads();
#pragma unroll 1
    for (int kp = 0; kp < 2; ++kp) {
      int k0l = kp * 64 + kg * 8;                 // within-half k base
      float z[8][4];
#pragma unroll
      for (int i = 0; i < 8; ++i) {
        z[i][0] = cv.x; z[i][1] = cv.y; z[i][2] = cv.z; z[i][3] = cv.w;
      }
#pragma unroll 8
      for (int jj = 0; jj < 32; ++jj) {
        float xv = xi1s[nn][jj];
        const float4* mr = (const float4*)&m1t[jj * 128 + k0l];
        float4 ma = mr[0], mb = mr[1];
        const float4 w = w2s4[jj * 8 + qg];
        float h0 = fmaxf(0.f, xv + ma.x), h1 = fmaxf(0.f, xv + ma.y);
        float h2 = fmaxf(0.f, xv + ma.z), h3 = fmaxf(0.f, xv + ma.w);
        float h4 = fmaxf(0.f, xv + mb.x), h5 = fmaxf(0.f, xv + mb.y);
        float h6 = fmaxf(0.f, xv + mb.z), h7 = fmaxf(0.f, xv + mb.w);
#define ZROW(i, hh) \
        z[i][0] += hh * w.x; z[i][1] += hh * w.y; \
        z[i][2] += hh * w.z; z[i][3] += hh * w.w;
        ZROW(0, h0) ZROW(1, h1) ZROW(2, h2) ZROW(3, h3)
        ZROW(4, h4) ZROW(5, h5) ZROW(6, h6) ZROW(7, h7)
#undef ZROW
      }
      // epilogue: w3 partial dot, butterfly over the 8 qg lanes
      float s[8];
#pragma unroll
      for (int i = 0; i < 8; ++i)
        s[i] = fmaxf(0.f, z[i][0]) * w3v.x + fmaxf(0.f, z[i][1]) * w3v.y
             + fmaxf(0.f, z[i][2]) * w3v.z + fmaxf(0.f, z[i][3]) * w3v.w;
#pragma unroll
      for (int i = 0; i < 8; ++i) {
        s[i] += __shfl_xor(s[i], 1, 64);
        s[i] += __shfl_xor(s[i], 2, 64);
        s[i] += __shfl_xor(s[i], 4, 64);
      }
      // lane qg owns k = kh*128 + k0l + qg; 8-way ternary (rule #20)
      float sv = qg < 4 ? (qg < 2 ? (qg == 0 ? s[0] : s[1]) : (qg == 2 ? s[2] : s[3]))
                        : (qg < 6 ? (qg == 4 ? s[4] : s[5]) : (qg == 6 ? s[6] : s[7]));
      int kown = kh * 128 + k0l + qg;
      float P = 1.f / (1.f + expf(-(sv + b3)));
      Pis[nn][kown] = P * nekl[kown];
    }
    __syncthreads();                              // m1t reuse / Pis publish
  }
  // ---- ctx phases ----
  // sums over k (Pe = nek - Pi)
  if (tid < 128) {
    int n4 = tid >> 5, jx = tid & 31;
    float s1 = 0.f, s2 = 0.f;
#pragma unroll
    for (int t = 0; t < 8; ++t) {
      float pi = Pis[n4][jx + 32 * t];
      s1 += pi;
      s2 += nekl[jx + 32 * t] - pi;
    }
    for (int off = 16; off > 0; off >>= 1) {
      s1 += __shfl_down(s1, off, 32);
      s2 += __shfl_down(s2, off, 32);
    }
    if (jx == 0) { sI[n4] = s1; sE[n4] = s2; }
  }
  __syncthreads();
  // x_intra/x_inter: thread = (n, c)
  {
    int c = tid & 63, n = tid >> 6;
    const float4* PI4 = (const float4*)Pis[n];
    const float4* NE4 = (const float4*)nekl;
    const float* tfg = ws + OFF_TF + (size_t)b * KK * CC + c;
    float aI = 0.f, aE = 0.f;
#pragma unroll 4
    for (int kq = 0; kq < 64; ++kq) {
      float4 piv = PI4[kq], nev = NE4[kq];
      float t0 = tfg[(4 * kq + 0) * 64];
      float t1 = tfg[(4 * kq + 1) * 64];
      float t2 = tfg[(4 * kq + 2) * 64];
      float t3 = tfg[(4 * kq + 3) * 64];
      aI += piv.x * t0 + piv.y * t1 + piv.z * t2 + piv.w * t3;
      aE += (nev.x - piv.x) * t0 + (nev.y - piv.y) * t1
          + (nev.z - piv.z) * t2 + (nev.w - piv.w) * t3;
    }
    xIl[n * 68 + c] = aI / sI[n];
    xEl[n * 68 + c] = aE / sE[n];
  }
  __syncthreads();
  // delta = xI @ WF[64:128] + xE @ WF[128:192]
  {
    int co = tid & 63, n4 = tid >> 6;
    const float4* xI4 = (const float4*)&xIl[n4 * 68];
    const float4* xE4 = (const float4*)&xEl[n4 * 68];
    const float* wI = ws + OFF_WF + 64 * CC + co;
    const float* wE = ws + OFF_WF + 128 * CC + co;
    float dsum = 0.f;
#pragma unroll 4
    for (int cq = 0; cq < 16; ++cq) {
      float4 xi4 = xI4[cq], xe4 = xE4[cq];
      dsum += xi4.x * wI[(4 * cq + 0) * 64] + xi4.y * wI[(4 * cq + 1) * 64]
            + xi4.z * wI[(4 * cq + 2) * 64] + xi4.w * wI[(4 * cq + 3) * 64];
      dsum += xe4.x * wE[(4 * cq + 0) * 64] + xe4.y * wE[(4 * cq + 1) * 64]
            + xe4.z * wE[(4 * cq + 2) * 64] + xe4.w * wE[(4 * cq + 3) * 64];
    }
    ws[OFF_DELTA + (size_t)(b * NN + n0 + n4) * CC + co] = dsum;
  }
}

// ---------------- K4: base resize + delta add; widened grid (8 blocks/CU)
// co split into quarters: grid = BS*FLAT/64 * 4 = 2048, 4 outputs/thread.
// Input re-read x4 is L2-absorbed (~33 MB @ 34 TB/s).
__global__ __launch_bounds__(256) void k4_out(
    const float* __restrict__ input, float* __restrict__ out,
    const float* __restrict__ ws) {
  __shared__ __align__(16) float wfa[64 * 16];
  __shared__ float bfl[16];
  int tid = threadIdx.x;
  int cq = blockIdx.x & 3, pgrp = blockIdx.x >> 2;
  const float* wf = ws + OFF_WF;
  for (int e = tid; e < 1024; e += 256) {
    int c = e >> 4, i = e & 15;
    wfa[e] = wf[c * 64 + cq * 16 + i] + wf[(192 + c) * 64 + cq * 16 + i];
  }
  if (tid < 16) bfl[tid] = ws[OFF_BF + cq * 16 + tid];
  __syncthreads();
  int q = tid >> 6, lane = tid & 63;           // q wave-uniform
  int pg = pgrp * 64 + lane;
  int b = pg >> 14, pos = pg & (FLAT - 1);
  const int* inv = (const int*)(ws + OFF_INV);
  float acc[4];
#pragma unroll
  for (int u = 0; u < 4; ++u) acc[u] = bfl[q * 4 + u];
#pragma unroll 4
  for (int c = 0; c < 64; ++c) {
    float xv = input[((size_t)(b * CC + c)) * FLAT + pos];
    float4 w = *(const float4*)&wfa[c * 16 + q * 4];   // broadcast
    acc[0] += xv * w.x; acc[1] += xv * w.y;
    acc[2] += xv * w.z; acc[3] += xv * w.w;
  }
  int n = inv[pg];
  if (n >= 0) {
    float4 dv = *(const float4*)(ws + OFF_DELTA +
                  (size_t)(b * NN + n) * CC + cq * 16 + q * 4);
    acc[0] += dv.x; acc[1] += dv.y; acc[2] += dv.z; acc[3] += dv.w;
  }
#pragma unroll
  for (int u = 0; u < 4; ++u)
    out[((size_t)(b * CC + cq * 16 + q * 4 + u)) * FLAT + pos] = acc[u];
}

// ---------------- launch ----------------
extern "C" void kernel_launch(void* const* d_in, const int* in_sizes, int n_in,
                              void* d_out, int out_size, void* d_ws, size_t ws_size,
                              hipStream_t stream) {
  const float* input = (const float*)d_in[0];
  const int*   midx  = (const int*)  d_in[1];
  const float* w_ne1 = (const float*)d_in[2];
  const float* b_ne1 = (const float*)d_in[3];
  const float* g_ne  = (const float*)d_in[4];
  const float* be_ne = (const float*)d_in[5];
  const float* w_ne2 = (const float*)d_in[6];
  const float* b_ne2 = (const float*)d_in[7];
  const float* w_p1  = (const float*)d_in[8];
  const float* b_p1  = (const float*)d_in[9];
  const float* g_p1  = (const float*)d_in[10];
  const float* be_p1 = (const float*)d_in[11];
  const float* w_p2  = (const float*)d_in[12];
  const float* b_p2  = (const float*)d_in[13];
  const float* g_p2  = (const float*)d_in[14];
  const float* be_p2 = (const float*)d_in[15];
  const float* w_p3  = (const float*)d_in[16];
  const float* b_p3  = (const float*)d_in[17];
  const float* w_r1  = (const float*)d_in[18];
  const float* b_r1  = (const float*)d_in[19];
  const float* w_r2  = (const float*)d_in[20];
  const float* b_r2  = (const float*)d_in[21];
  float* out = (float*)d_out;
  float* ws  = (float*)d_ws;

  k0_fold<<<dim3(256), dim3(64), 0, stream>>>(w_r1, b_r1, w_r2, b_r2, ws);
  k1_xi<<<dim3(BS * NN / 8), dim3(256), 0, stream>>>(
      input, midx, w_ne1, b_ne1, g_ne, be_ne, w_ne2, b_ne2, w_p1, g_p1, ws);
  k2_sample<<<dim3(BS * KK), dim3(256), 0, stream>>>(
      midx, w_p1, b_p1, g_p1, be_p1, ws);
  k3_fused<<<dim3(BS * NN / 4), dim3(256), 0, stream>>>(
      w_p2, b_p2, g_p2, be_p2, w_p3, b_p3, ws);
  k4_out<<<dim3(BS * FLAT / 64 * 4), dim3(256), 0, stream>>>(input, out, ws);
}